// Round 3
// baseline (258.400 us; speedup 1.0000x reference)
//
#include <hip/hip_runtime.h>
#include <hip/hip_cooperative_groups.h>
#include <stdint.h>

namespace cg = cooperative_groups;

#define SEQ   2048
#define BITS  256
#define HEADS 8
#define NPOS  4
#define MAXD  8
#define NBPN  12

typedef unsigned long long u64;
typedef unsigned int       u32;
typedef unsigned short     u16;

// ---- workspace layout (bytes) ----
#define OFF_TBL    0                 // 512 u64  (4096 B)  packed table bits
#define OFF_PACKED 4096              // SEQ*4 u64 (65536 B) packed token rows
#define OFF_AK     (4096 + 65536)    // SEQ*HEADS u16 (32768 B)

__device__ inline u64 shfl_down_u64(u64 x, int o) {
    u32 lo = (u32)x, hi = (u32)(x >> 32);
    lo = __shfl_down(lo, o, 64);
    hi = __shfl_down(hi, o, 64);
    return ((u64)hi << 32) | lo;
}

// Single fused kernel: 2048 blocks x 128 threads, all co-resident
// (launch_bounds(128,4): <=128 VGPR -> 16 waves/CU -> 8 blocks/CU x 256 CU).
// Phase 1: each block preps its own row (+ blocks 0..127 pack the table).
// grid.sync(). Phase 2: per-row vote/XOR scan with 2-j ILP.
__global__ __launch_bounds__(128, 4) void fused_kernel(
        const int* __restrict__ tokens, const int* __restrict__ head_idx,
        const float* __restrict__ table,
        u64* __restrict__ tblbits, u64* __restrict__ packed,
        u16* __restrict__ Ak, float* __restrict__ out) {

    __shared__ u32 tbl[HEADS * 128];        // 4 KB table bitmask (u32 words)
    __shared__ u16 aqar[MAXD + 1][HEADS];   // Aq[i]+Ar[d], this block's row
    __shared__ u16 s_aq[HEADS];
    __shared__ u64 p_acc[2][4];
    __shared__ int p_inc[2];
    __shared__ u64 p_key[2];

    const int b    = blockIdx.x;            // == row i
    const int tid  = threadIdx.x;
    const int lane = tid & 63, wave = tid >> 6;

    // ---------- phase 1: prep ----------
    // pack this row's 256 token bits (2 ballots per wave)
    {
        int c0 = b * 256 + wave * 64 + lane;
        u64 m0 = __ballot(tokens[c0] & 1);
        u64 m1 = __ballot(tokens[c0 + 128] & 1);
        if (lane == 0) { packed[b * 4 + wave] = m0; packed[b * 4 + wave + 2] = m1; }
    }
    // blocks 0..127 pack the 32768-bit table (256 bits each)
    if (b < 128) {
        int t0 = b * 256 + wave * 64 + lane;
        u64 q0 = __ballot(table[t0] != 0.0f);
        u64 q1 = __ballot(table[t0 + 128] != 0.0f);
        if (lane == 0) { tblbits[b * 4 + wave] = q0; tblbits[b * 4 + wave + 2] = q1; }
    }
    // Aq (LDS-only) and Ak (global) for this row: thread h in [0,8)
    if (tid < HEADS) {
        const int* hi  = head_idx + tid * NBPN;
        const int* tok = tokens + b * 256;
        int aq = 0, ak = 0;
        #pragma unroll
        for (int k = 0; k < NBPN; ++k) {
            int idx = hi[k];
            if (idx < BITS)          aq += tok[idx] << k;
            else if (idx < 2 * BITS) ak += tok[idx - BITS] << k;
        }
        s_aq[tid] = (u16)aq;
        Ak[b * HEADS + tid] = (u16)ak;
    }
    __syncthreads();
    // fused Aq+Ar bases per distance: threads 0..71
    if (tid < (MAXD + 1) * HEADS) {
        int d = tid >> 3, h = tid & 7;
        const int* hi = head_idx + h * NBPN;
        int ar = 0;
        #pragma unroll
        for (int k = 0; k < NBPN; ++k) {
            int idx = hi[k];
            if (idx >= 2 * BITS) ar += ((d >> (idx - 2 * BITS)) & 1) << k;
        }
        aqar[d][h] = (u16)(s_aq[h] + ar);
    }

    __threadfence();
    cg::this_grid().sync();

    // ---------- phase 2: per-row scan ----------
    const u32* tb32 = (const u32*)tblbits;
    #pragma unroll
    for (int w = 0; w < 8; ++w) tbl[tid + w * 128] = tb32[tid + w * 128];
    __syncthreads();

    const int i = b;
    u32 a8[8];                               // dist>=8 bases in registers
    #pragma unroll
    for (int h = 0; h < 8; ++h) a8[h] = aqar[MAXD][h];

    u64 acc0 = 0, acc1 = 0, acc2 = 0, acc3 = 0;
    int inc = 0;
    u64 bestkey = 0;

    for (int j0 = tid; j0 <= i; j0 += 256) {
        // ---- pair A: j = j0 (always valid) ----
        {
            const int j = j0, dist = i - j;
            const uint4 akv = *(const uint4*)(Ak + j * HEADS);
            int votes = 0;
            if (__any(dist < MAXD)) {
                #pragma unroll
                for (int h = 0; h < 8; ++h) {
                    u32 ak_h = ((&akv.x)[h >> 1] >> ((h & 1) * 16)) & 0xFFFFu;
                    u32 base = (dist >= MAXD) ? a8[h] : (u32)aqar[dist][h];
                    u32 addr = base + ak_h;
                    votes += (int)((tbl[(h << 7) + (addr >> 5)] >> (addr & 31)) & 1u);
                }
            } else {
                #pragma unroll
                for (int h = 0; h < 8; ++h) {
                    u32 ak_h = ((&akv.x)[h >> 1] >> ((h & 1) * 16)) & 0xFFFFu;
                    u32 addr = a8[h] + ak_h;
                    votes += (int)((tbl[(h << 7) + (addr >> 5)] >> (addr & 31)) & 1u);
                }
            }
            int att = (votes >= HEADS / 2) ? 1 : 0;
            u64 m = (u64)0 - (u64)att;
            const ulonglong2* pj = (const ulonglong2*)(packed + j * 4);
            ulonglong2 pA = pj[0], pB = pj[1];
            acc0 ^= pA.x & m; acc1 ^= pA.y & m;
            acc2 ^= pB.x & m; acc3 ^= pB.y & m;
            inc += att;
            u64 key = ((u64)(votes + 1) << 32) | (u64)(0x7FFFFFFF - j);
            if (key > bestkey) bestkey = key;
        }
        // ---- pair B: j = j0 + 128 (masked near the diagonal) ----
        {
            const int jB = j0 + 128;
            if (__any(jB <= i)) {
                const bool v = (jB <= i);
                const int j = v ? jB : i;       // clamp keeps loads in-bounds
                const int dist = i - j;
                const uint4 akv = *(const uint4*)(Ak + j * HEADS);
                int votes = 0;
                if (__any(dist < MAXD)) {
                    #pragma unroll
                    for (int h = 0; h < 8; ++h) {
                        u32 ak_h = ((&akv.x)[h >> 1] >> ((h & 1) * 16)) & 0xFFFFu;
                        u32 base = (dist >= MAXD) ? a8[h] : (u32)aqar[dist][h];
                        u32 addr = base + ak_h;
                        votes += (int)((tbl[(h << 7) + (addr >> 5)] >> (addr & 31)) & 1u);
                    }
                } else {
                    #pragma unroll
                    for (int h = 0; h < 8; ++h) {
                        u32 ak_h = ((&akv.x)[h >> 1] >> ((h & 1) * 16)) & 0xFFFFu;
                        u32 addr = a8[h] + ak_h;
                        votes += (int)((tbl[(h << 7) + (addr >> 5)] >> (addr & 31)) & 1u);
                    }
                }
                int att = (v && votes >= HEADS / 2) ? 1 : 0;
                u64 m = (u64)0 - (u64)att;
                const ulonglong2* pj = (const ulonglong2*)(packed + j * 4);
                ulonglong2 pA = pj[0], pB = pj[1];
                acc0 ^= pA.x & m; acc1 ^= pA.y & m;
                acc2 ^= pB.x & m; acc3 ^= pB.y & m;
                inc += att;
                if (v) {
                    u64 key = ((u64)(votes + 1) << 32) | (u64)(0x7FFFFFFF - j);
                    if (key > bestkey) bestkey = key;
                }
            }
        }
    }

    #pragma unroll
    for (int o = 32; o > 0; o >>= 1) {
        acc0 ^= shfl_down_u64(acc0, o);
        acc1 ^= shfl_down_u64(acc1, o);
        acc2 ^= shfl_down_u64(acc2, o);
        acc3 ^= shfl_down_u64(acc3, o);
        inc  += __shfl_down(inc, o, 64);
        u64 k2 = shfl_down_u64(bestkey, o);
        if (k2 > bestkey) bestkey = k2;
    }
    if (lane == 0) {
        p_acc[wave][0] = acc0; p_acc[wave][1] = acc1;
        p_acc[wave][2] = acc2; p_acc[wave][3] = acc3;
        p_inc[wave] = inc; p_key[wave] = bestkey;
    }
    __syncthreads();

    u64 f0 = p_acc[0][0] ^ p_acc[1][0];
    u64 f1 = p_acc[0][1] ^ p_acc[1][1];
    u64 f2 = p_acc[0][2] ^ p_acc[1][2];
    u64 f3 = p_acc[0][3] ^ p_acc[1][3];
    int finc = p_inc[0] + p_inc[1];
    u64 fk = (p_key[0] > p_key[1]) ? p_key[0] : p_key[1];

    int b0   = tid * 2;                     // 2 output bits per thread
    int wsel = tid >> 5;
    u64 word;
    if (finc > 0) {
        word = (wsel < 2) ? (wsel == 0 ? f0 : f1) : (wsel == 2 ? f2 : f3);
    } else {
        int bestj = 0x7FFFFFFF - (int)(fk & 0xFFFFFFFFu);
        word = packed[bestj * 4 + wsel];
    }
    int sh = b0 & 63;
    float2 o2 = make_float2((float)((word >> sh) & 1ull),
                            (float)((word >> (sh + 1)) & 1ull));
    *(float2*)(out + i * BITS + b0) = o2;
}

extern "C" void kernel_launch(void* const* d_in, const int* in_sizes, int n_in,
                              void* d_out, int out_size, void* d_ws, size_t ws_size,
                              hipStream_t stream) {
    const int*   tokens   = (const int*)d_in[0];
    const int*   head_idx = (const int*)d_in[1];
    const float* table    = (const float*)d_in[2];
    float*       out      = (float*)d_out;
    char*        ws       = (char*)d_ws;

    u64* tblbits = (u64*)(ws + OFF_TBL);
    u64* packed  = (u64*)(ws + OFF_PACKED);
    u16* Ak      = (u16*)(ws + OFF_AK);

    void* args[] = { (void*)&tokens, (void*)&head_idx, (void*)&table,
                     (void*)&tblbits, (void*)&packed, (void*)&Ak, (void*)&out };
    hipLaunchCooperativeKernel((void*)fused_kernel, dim3(SEQ), dim3(128),
                               args, 0, stream);
}

// Round 4
// 75.702 us; speedup vs baseline: 3.4134x; 3.4134x over previous
//
#include <hip/hip_runtime.h>
#include <stdint.h>

#define SEQ   2048
#define BITS  256
#define HEADS 8
#define NPOS  4
#define MAXD  8
#define NBPN  12

typedef unsigned long long u64;
typedef unsigned int       u32;
typedef unsigned short     u16;

// ---- workspace layout (bytes) ----
#define OFF_TBL    0                         // 512 u64   (4096 B)
#define OFF_PACKED 4096                      // SEQ*4 u64 (65536 B)
#define OFF_AQ     (4096 + 65536)            // SEQ*HEADS u16 (32768 B)
#define OFF_AK     (4096 + 65536 + 32768)    // SEQ*HEADS u16 (32768 B)
#define OFF_AR     (4096 + 65536 + 65536)    // 9*HEADS u16 (144 B)

// One fused prep kernel (R2 structure — measured ~2 us incl. launch).
//   [0, 2048)    : pack tokens via ballot   (SEQ*BITS bits)
//   [2048, 2176) : pack table via ballot    (HEADS*4096 bits)
//   [2176, 2240) : Aq/Ak/Ar address parts
__global__ __launch_bounds__(256) void prep_kernel(
        const int* __restrict__ tokens, const int* __restrict__ head_idx,
        const float* __restrict__ table,
        u64* __restrict__ tblbits, u64* __restrict__ packed,
        u16* __restrict__ Aq, u16* __restrict__ Ak, u16* __restrict__ Ar) {
    const int bid = blockIdx.x, tid = threadIdx.x;
    if (bid < 2048) {
        int t = bid * 256 + tid;
        u64 m = __ballot(tokens[t] & 1);
        if ((tid & 63) == 0) packed[t >> 6] = m;
    } else if (bid < 2048 + 128) {
        int t = (bid - 2048) * 256 + tid;
        u64 m = __ballot(table[t] != 0.0f);
        if ((tid & 63) == 0) tblbits[t >> 6] = m;
    } else {
        int t = (bid - 2176) * 256 + tid;        // 0..16383
        int s = t >> 3, h = t & 7;
        const int* hi  = head_idx + h * NBPN;
        const int* tok = tokens + s * BITS;
        int aq = 0, ak = 0;
        #pragma unroll
        for (int k = 0; k < NBPN; ++k) {
            int idx = hi[k];
            if (idx < BITS)          aq += tok[idx] << k;
            else if (idx < 2 * BITS) ak += tok[idx - BITS] << k;
        }
        Aq[t] = (u16)aq;
        Ak[t] = (u16)ak;
        if (t < (MAXD + 1) * HEADS) {            // 72 threads also fill Ar
            int d = t / HEADS, hh = t % HEADS;
            const int* hi2 = head_idx + hh * NBPN;
            int ar = 0;
            #pragma unroll
            for (int k = 0; k < NBPN; ++k) {
                int idx = hi2[k];
                if (idx >= 2 * BITS) ar += ((d >> (idx - 2 * BITS)) & 1) << k;
            }
            Ar[t] = (u16)ar;
        }
    }
}

__device__ inline u64 shfl_down_u64(u64 x, int o) {
    u32 lo = (u32)x, hi = (u32)(x >> 32);
    lo = __shfl_down(lo, o, 64);
    hi = __shfl_down(hi, o, 64);
    return ((u64)hi << 32) | lo;
}

// One row per block, 2 waves. Near-diagonal (dist<8, <=8 j's) peeled to
// threads 0..7; main loop is branch-free (constant a8 base) with explicit
// next-iteration prefetch of Ak/packed so <=16 iters expose ~1 L2 latency.
__global__ __launch_bounds__(128) void row_kernel(
        const u64* __restrict__ tblbits, const u64* __restrict__ packed,
        const u16* __restrict__ Aq, const u16* __restrict__ Ak,
        const u16* __restrict__ Ar, float* __restrict__ out) {

    __shared__ u32 tbl[HEADS * 128];       // 4 KB table bitmask (u32 words)
    __shared__ u16 aqar[MAXD + 1][HEADS];
    __shared__ u64 p_acc[2][4];
    __shared__ int p_inc[2];
    __shared__ u64 p_key[2];

    const int i   = blockIdx.x;
    const int tid = threadIdx.x;

    const u32* tb32 = (const u32*)tblbits;
    #pragma unroll
    for (int w = 0; w < 8; ++w) tbl[tid + w * 128] = tb32[tid + w * 128];
    if (tid < (MAXD + 1) * HEADS) {
        int h = tid & 7;
        aqar[tid >> 3][h] = (u16)(Aq[i * HEADS + h] + Ar[tid]);
    }
    __syncthreads();

    u32 a8[8];
    #pragma unroll
    for (int h = 0; h < 8; ++h) a8[h] = aqar[MAXD][h];

    u64 acc0 = 0, acc1 = 0, acc2 = 0, acc3 = 0;
    int inc = 0;
    u64 bestkey = 0;

    // ---- peel: dist = tid in [0,8), j = i - dist ----
    if (tid < MAXD) {
        int j = i - tid;
        if (j >= 0) {
            const uint4 akv = *(const uint4*)(Ak + j * HEADS);
            int votes = 0;
            #pragma unroll
            for (int h = 0; h < 8; ++h) {
                u32 ak_h = ((&akv.x)[h >> 1] >> ((h & 1) * 16)) & 0xFFFFu;
                u32 addr = (u32)aqar[tid][h] + ak_h;
                votes += (int)((tbl[(h << 7) + (addr >> 5)] >> (addr & 31)) & 1u);
            }
            int att = (votes >= HEADS / 2) ? 1 : 0;
            u64 m = (u64)0 - (u64)att;
            const ulonglong2* pj = (const ulonglong2*)(packed + j * 4);
            ulonglong2 pA = pj[0], pB = pj[1];
            acc0 ^= pA.x & m; acc1 ^= pA.y & m;
            acc2 ^= pB.x & m; acc3 ^= pB.y & m;
            inc += att;
            u64 key = ((u64)(votes + 1) << 32) | (u64)(0x7FFFFFFF - j);
            if (key > bestkey) bestkey = key;
        }
    }

    // ---- main: j <= i - 8, branch-free base, prefetched ----
    const int ilim = i - MAXD;
    int j = tid;
    uint4 akv; ulonglong2 pA, pB;
    if (j <= ilim) {
        akv = *(const uint4*)(Ak + j * HEADS);
        const ulonglong2* pj = (const ulonglong2*)(packed + j * 4);
        pA = pj[0]; pB = pj[1];
    }
    while (j <= ilim) {
        const int jn = j + 128;
        uint4 akv_n; ulonglong2 pA_n, pB_n;
        if (jn <= ilim) {                  // prefetch next tile
            akv_n = *(const uint4*)(Ak + jn * HEADS);
            const ulonglong2* pjn = (const ulonglong2*)(packed + jn * 4);
            pA_n = pjn[0]; pB_n = pjn[1];
        }
        int votes = 0;
        #pragma unroll
        for (int h = 0; h < 8; ++h) {
            u32 ak_h = ((&akv.x)[h >> 1] >> ((h & 1) * 16)) & 0xFFFFu;
            u32 addr = a8[h] + ak_h;       // < 4096 (disjoint bit masks)
            votes += (int)((tbl[(h << 7) + (addr >> 5)] >> (addr & 31)) & 1u);
        }
        int att = (votes >= HEADS / 2) ? 1 : 0;
        u64 m = (u64)0 - (u64)att;
        acc0 ^= pA.x & m; acc1 ^= pA.y & m;
        acc2 ^= pB.x & m; acc3 ^= pB.y & m;
        inc += att;
        u64 key = ((u64)(votes + 1) << 32) | (u64)(0x7FFFFFFF - j);
        if (key > bestkey) bestkey = key;
        j = jn; akv = akv_n; pA = pA_n; pB = pB_n;
    }

    #pragma unroll
    for (int o = 32; o > 0; o >>= 1) {
        acc0 ^= shfl_down_u64(acc0, o);
        acc1 ^= shfl_down_u64(acc1, o);
        acc2 ^= shfl_down_u64(acc2, o);
        acc3 ^= shfl_down_u64(acc3, o);
        inc  += __shfl_down(inc, o, 64);
        u64 k2 = shfl_down_u64(bestkey, o);
        if (k2 > bestkey) bestkey = k2;
    }
    int wave = tid >> 6;
    if ((tid & 63) == 0) {
        p_acc[wave][0] = acc0; p_acc[wave][1] = acc1;
        p_acc[wave][2] = acc2; p_acc[wave][3] = acc3;
        p_inc[wave] = inc; p_key[wave] = bestkey;
    }
    __syncthreads();

    u64 f0 = p_acc[0][0] ^ p_acc[1][0];
    u64 f1 = p_acc[0][1] ^ p_acc[1][1];
    u64 f2 = p_acc[0][2] ^ p_acc[1][2];
    u64 f3 = p_acc[0][3] ^ p_acc[1][3];
    int finc = p_inc[0] + p_inc[1];
    u64 fk = (p_key[0] > p_key[1]) ? p_key[0] : p_key[1];

    int b0   = tid * 2;                    // 2 output bits per thread
    int wsel = tid >> 5;
    u64 word;
    if (finc > 0) {
        word = (wsel < 2) ? (wsel == 0 ? f0 : f1) : (wsel == 2 ? f2 : f3);
    } else {
        int bestj = 0x7FFFFFFF - (int)(fk & 0xFFFFFFFFu);
        word = packed[bestj * 4 + wsel];
    }
    int sh = b0 & 63;
    float2 o2 = make_float2((float)((word >> sh) & 1ull),
                            (float)((word >> (sh + 1)) & 1ull));
    *(float2*)(out + i * BITS + b0) = o2;
}

extern "C" void kernel_launch(void* const* d_in, const int* in_sizes, int n_in,
                              void* d_out, int out_size, void* d_ws, size_t ws_size,
                              hipStream_t stream) {
    const int*   tokens   = (const int*)d_in[0];
    const int*   head_idx = (const int*)d_in[1];
    const float* table    = (const float*)d_in[2];
    float*       out      = (float*)d_out;
    char*        ws       = (char*)d_ws;

    u64* tblbits = (u64*)(ws + OFF_TBL);
    u64* packed  = (u64*)(ws + OFF_PACKED);
    u16* Aq      = (u16*)(ws + OFF_AQ);
    u16* Ak      = (u16*)(ws + OFF_AK);
    u16* Ar      = (u16*)(ws + OFF_AR);

    prep_kernel<<<2240, 256, 0, stream>>>(tokens, head_idx, table,
                                          tblbits, packed, Aq, Ak, Ar);
    row_kernel <<<SEQ, 128, 0, stream>>>(tblbits, packed, Aq, Ak, Ar, out);
}